// Round 1
// baseline (177.061 us; speedup 1.0000x reference)
//
#include <hip/hip_runtime.h>
#include <hip/hip_bf16.h>

// Problem constants (from reference)
#define BB   4096
#define MM   200
#define DD   100
#define NENT 5000

// ws layout (bytes):
//   Pr : bf16[5000][100]  @ 0         (1,000,000 B)  = sym@W[:, :D]^T + (gcn_w_bias+gcn_b)
//   Pe : bf16[5000][100]  @ 1,000,000 (1,000,000 B)  = sym@W[:, D:]^T
//   Sy : bf16[5000][100]  @ 2,000,000 (1,000,000 B)  = bf16(sym[e])
// total 3,000,000 B

__device__ __forceinline__ float bf16lo(unsigned u) {
    return __uint_as_float(u << 16);
}
__device__ __forceinline__ float bf16hi(unsigned u) {
    return __uint_as_float(u & 0xffff0000u);
}
__device__ __forceinline__ unsigned short f2bf(float f) {
    unsigned u = __float_as_uint(f);
    unsigned r = (u + 0x7fffu + ((u >> 16) & 1u)) >> 16;  // round-to-nearest-even
    return (unsigned short)r;
}

// ---------------------------------------------------------------------------
// Kernel A: project the 5000 usable symbol rows through both halves of W.
// Pr[e][d] = sum_k sym[e][k]*W[d][k] + wb[d] + gb[d]
// Pe[e][d] = sum_k sym[e][k]*W[d][100+k]
// Sy[e][d] = bf16(sym[e][d])
// Thread = (e, dp) pair, dp covers d = 2dp, 2dp+1. 5000*50 = 250,000 threads.
// W is staged transposed in LDS as bf16 so the inner loop reads one u32 per
// (row-pair, k): Wt[k][d], row stride 102 u16 (odd u32 stride -> no conflicts).
// ---------------------------------------------------------------------------
__global__ __launch_bounds__(256) void precompute_kernel(
    const float* __restrict__ sym, const float* __restrict__ W,
    const float* __restrict__ wb, const float* __restrict__ gb,
    unsigned short* __restrict__ Pr, unsigned short* __restrict__ Pe,
    unsigned short* __restrict__ Sy)
{
    __shared__ unsigned short Wt[200 * 102];
    const int tid = threadIdx.x;
    for (int j = tid; j < 20000; j += 256) {
        int d = j / 200, k = j % 200;          // W[d][k], coalesced global read
        Wt[k * 102 + d] = f2bf(W[j]);
    }
    __syncthreads();

    const int i = blockIdx.x * 256 + tid;
    if (i >= NENT * 50) return;
    const int e = i / 50, dp = i % 50;
    const float* se = sym + e * DD;

    float pr0 = 0.f, pr1 = 0.f, pe0 = 0.f, pe1 = 0.f;
    for (int k = 0; k < 100; k++) {
        float a = se[k];  // broadcast within 50-lane group
        unsigned w01 = *(const unsigned*)&Wt[k * 102 + 2 * dp];         // W[d0][k], W[d0+1][k]
        unsigned w23 = *(const unsigned*)&Wt[(k + 100) * 102 + 2 * dp]; // W[d0][100+k], W[d0+1][100+k]
        pr0 = fmaf(a, bf16lo(w01), pr0);
        pr1 = fmaf(a, bf16hi(w01), pr1);
        pe0 = fmaf(a, bf16lo(w23), pe0);
        pe1 = fmaf(a, bf16hi(w23), pe1);
    }
    const int d0 = 2 * dp;
    pr0 += wb[d0]     + gb[d0];
    pr1 += wb[d0 + 1] + gb[d0 + 1];

    unsigned prp = (unsigned)f2bf(pr0) | ((unsigned)f2bf(pr1) << 16);
    unsigned pep = (unsigned)f2bf(pe0) | ((unsigned)f2bf(pe1) << 16);
    unsigned syp = (unsigned)f2bf(se[d0]) | ((unsigned)f2bf(se[d0 + 1]) << 16);
    *(unsigned*)&Pr[e * DD + d0] = prp;
    *(unsigned*)&Pe[e * DD + d0] = pep;
    *(unsigned*)&Sy[e * DD + d0] = syp;
}

// ---------------------------------------------------------------------------
// Kernel B: one block per batch row b. Fully fused:
//   gather Pr/Pe -> leaky_relu -> out (LDS, packed bf16) -> attn logits ->
//   softmax(m) -> out_attn -> gate -> + entself*(1-g) + neighbor sum
// ---------------------------------------------------------------------------
__global__ __launch_bounds__(256) void main_kernel(
    const int*  __restrict__ conn, const int* __restrict__ target,
    const float* __restrict__ sym, const float* __restrict__ co,
    const unsigned short* __restrict__ Pr, const unsigned short* __restrict__ Pe,
    const unsigned short* __restrict__ Sy,
    const float* __restrict__ attn_w, const float* __restrict__ attn_b,
    const float* __restrict__ gate_w, const float* __restrict__ gate_wb,
    const float* __restrict__ gate_b,
    float* __restrict__ outp)
{
    __shared__ int   rel[MM];
    __shared__ int   ent[MM];
    __shared__ float co_w[MM];
    __shared__ float l_lds[MM];
    __shared__ float w_lds[MM];
    __shared__ unsigned out_lds[MM * 51];  // packed bf16 pairs, row stride 51 u32 (odd)
    __shared__ float red[16];
    __shared__ int   s_self, s_tgt;

    const int tid = threadIdx.x;
    const int b = blockIdx.x;
    const int* cb = conn + b * (MM * 3);

    if (tid < MM) {
        rel[tid] = cb[tid * 3 + 1];
        ent[tid] = cb[tid * 3 + 2];
    }
    if (tid == 0) { s_self = cb[0]; s_tgt = target[b * 2]; }
    __syncthreads();                                   // sync 1

    // co_weight gather — scattered; issue early so latency overlaps phase 2
    if (tid < MM) co_w[tid] = co[ent[tid] * NENT + s_tgt];

    // phase 2: out[m][d] = lrelu(Pr[rel[m]][d] + Pe[ent[m]][d])  (d-pairs)
    for (int i = tid; i < MM * 50; i += 256) {
        int m = i / 50, dp = i % 50;
        unsigned pru = *(const unsigned*)&Pr[rel[m] * DD + 2 * dp];
        unsigned peu = *(const unsigned*)&Pe[ent[m] * DD + 2 * dp];
        float x0 = bf16lo(pru) + bf16lo(peu);
        float x1 = bf16hi(pru) + bf16hi(peu);
        x0 = fmaxf(x0, 0.01f * x0);
        x1 = fmaxf(x1, 0.01f * x1);
        out_lds[m * 51 + dp] = (unsigned)f2bf(x0) | ((unsigned)f2bf(x1) << 16);
    }
    __syncthreads();                                   // sync 2

    // phase 3: attention logits, one m per thread
    if (tid < MM) {
        float acc = 0.f;
        const unsigned* row = &out_lds[tid * 51];
        for (int dp = 0; dp < 50; dp++) {
            unsigned u = row[dp];
            acc = fmaf(bf16lo(u), attn_w[2 * dp], acc);
            acc = fmaf(bf16hi(u), attn_w[2 * dp + 1], acc);
        }
        l_lds[tid] = acc + attn_b[0];
    }
    __syncthreads();                                   // sync 3

    // softmax over the 200 logits
    const int lane = tid & 63, wid = tid >> 6;
    float v = (tid < MM) ? l_lds[tid] : -3.0e38f;
    for (int off = 32; off >= 1; off >>= 1) v = fmaxf(v, __shfl_xor(v, off));
    if (lane == 0) red[wid] = v;
    __syncthreads();                                   // sync 4
    float gmax = fmaxf(fmaxf(red[0], red[1]), fmaxf(red[2], red[3]));
    float e = (tid < MM) ? __expf(l_lds[tid] - gmax) : 0.f;
    float s = e;
    for (int off = 32; off >= 1; off >>= 1) s += __shfl_xor(s, off);
    if (lane == 0) red[8 + wid] = s;
    __syncthreads();                                   // sync 5
    float gsum = red[8] + red[9] + red[10] + red[11];
    if (tid < MM) w_lds[tid] = e / gsum;
    __syncthreads();                                   // sync 6

    // phase 4: out_attn[d] and neighbor_emb[d], one d per thread (d < 100)
    float oa = 0.f, nb = 0.f;
    if (tid < DD) {
        for (int m = 0; m < MM; m++) {
            unsigned ou = out_lds[m * 51 + (tid >> 1)];
            float ov = (tid & 1) ? bf16hi(ou) : bf16lo(ou);
            oa = fmaf(w_lds[m], ov, oa);
            float sv = __uint_as_float(((unsigned)Sy[ent[m] * DD + tid]) << 16);
            nb = fmaf(co_w[m], sv, nb);
        }
    }

    // gate = sigmoid(dot(out_attn, gate_w) + gate_wb + gate_b)
    float p = (tid < DD) ? oa * gate_w[tid] : 0.f;
    for (int off = 32; off >= 1; off >>= 1) p += __shfl_xor(p, off);
    if (lane == 0) red[wid] = p;   // red[0..3] last read before sync 5 -> safe
    __syncthreads();                                   // sync 7
    float dot = red[0] + red[1] + red[2] + red[3];
    float g = 1.f / (1.f + __expf(-(dot + gate_wb[0] + gate_b[0])));

    if (tid < DD) {
        float self_v = sym[s_self * DD + tid];  // f32, exact
        outp[b * DD + tid] = oa * g + self_v * (1.f - g) + nb;
    }
}

extern "C" void kernel_launch(void* const* d_in, const int* in_sizes, int n_in,
                              void* d_out, int out_size, void* d_ws, size_t ws_size,
                              hipStream_t stream) {
    const int*   conn    = (const int*)  d_in[0];
    const int*   target  = (const int*)  d_in[1];
    const float* sym     = (const float*)d_in[2];
    const float* co      = (const float*)d_in[3];
    const float* W       = (const float*)d_in[4];
    const float* wb      = (const float*)d_in[5];
    const float* gb      = (const float*)d_in[6];
    const float* attn_w  = (const float*)d_in[7];
    const float* attn_b  = (const float*)d_in[8];
    const float* gate_w  = (const float*)d_in[9];
    const float* gate_wb = (const float*)d_in[10];
    const float* gate_b  = (const float*)d_in[11];

    unsigned short* Pr = (unsigned short*)d_ws;
    unsigned short* Pe = (unsigned short*)((char*)d_ws + 1000000);
    unsigned short* Sy = (unsigned short*)((char*)d_ws + 2000000);

    precompute_kernel<<<(NENT * 50 + 255) / 256, 256, 0, stream>>>(
        sym, W, wb, gb, Pr, Pe, Sy);

    main_kernel<<<BB, 256, 0, stream>>>(
        conn, target, sym, co, Pr, Pe, Sy,
        attn_w, attn_b, gate_w, gate_wb, gate_b, (float*)d_out);
}

// Round 2
// 83.683 us; speedup vs baseline: 2.1159x; 2.1159x over previous
//
#include <hip/hip_runtime.h>
#include <hip/hip_bf16.h>

// Problem constants (from reference)
#define BB   4096
#define MM   200
#define DD   100
#define NENT 5000
#define CH   100   // m-chunk for online softmax
#define NG   5     // m-groups per chunk
#define NDP  50    // d-pairs

// ws layout (bytes):
//   Pr : bf16[5000][100]  @ 0         = sym@W[:, :D]^T + (gcn_w_bias+gcn_b)
//   Pe : bf16[5000][100]  @ 1,000,000 = sym@W[:, D:]^T
//   Sy : bf16[5000][100]  @ 2,000,000 = bf16(sym[e])

__device__ __forceinline__ float bf16lo(unsigned u) {
    return __uint_as_float(u << 16);
}
__device__ __forceinline__ float bf16hi(unsigned u) {
    return __uint_as_float(u & 0xffff0000u);
}
__device__ __forceinline__ unsigned short f2bf(float f) {
    unsigned u = __float_as_uint(f);
    unsigned r = (u + 0x7fffu + ((u >> 16) & 1u)) >> 16;
    return (unsigned short)r;
}

// ---------------------------------------------------------------------------
// Kernel A: project the 5000 usable symbol rows through both halves of W.
// ---------------------------------------------------------------------------
__global__ __launch_bounds__(256) void precompute_kernel(
    const float* __restrict__ sym, const float* __restrict__ W,
    const float* __restrict__ wb, const float* __restrict__ gb,
    unsigned short* __restrict__ Pr, unsigned short* __restrict__ Pe,
    unsigned short* __restrict__ Sy)
{
    __shared__ unsigned short Wt[200 * 102];
    const int tid = threadIdx.x;
    for (int j = tid; j < 20000; j += 256) {
        int d = j / 200, k = j % 200;
        Wt[k * 102 + d] = f2bf(W[j]);
    }
    __syncthreads();

    const int i = blockIdx.x * 256 + tid;
    if (i >= NENT * 50) return;
    const int e = i / 50, dp = i % 50;
    const float* se = sym + e * DD;

    float pr0 = 0.f, pr1 = 0.f, pe0 = 0.f, pe1 = 0.f;
    for (int k = 0; k < 100; k++) {
        float a = se[k];
        unsigned w01 = *(const unsigned*)&Wt[k * 102 + 2 * dp];
        unsigned w23 = *(const unsigned*)&Wt[(k + 100) * 102 + 2 * dp];
        pr0 = fmaf(a, bf16lo(w01), pr0);
        pr1 = fmaf(a, bf16hi(w01), pr1);
        pe0 = fmaf(a, bf16lo(w23), pe0);
        pe1 = fmaf(a, bf16hi(w23), pe1);
    }
    const int d0 = 2 * dp;
    pr0 += wb[d0]     + gb[d0];
    pr1 += wb[d0 + 1] + gb[d0 + 1];

    unsigned prp = (unsigned)f2bf(pr0) | ((unsigned)f2bf(pr1) << 16);
    unsigned pep = (unsigned)f2bf(pe0) | ((unsigned)f2bf(pe1) << 16);
    unsigned syp = (unsigned)f2bf(se[d0]) | ((unsigned)f2bf(se[d0 + 1]) << 16);
    *(unsigned*)&Pr[e * DD + d0] = prp;
    *(unsigned*)&Pe[e * DD + d0] = pep;
    *(unsigned*)&Sy[e * DD + d0] = syp;
}

// ---------------------------------------------------------------------------
// Kernel B: one block per batch row; m chunked 2x100 with online softmax.
// Thread map for compute phases: t = g*50 + dp, g in [0,5), dp in [0,50).
// Each thread owns d-pair (2dp, 2dp+1) and m's {g, g+5, g+10, ...}.
// ---------------------------------------------------------------------------
__global__ __launch_bounds__(256) void main_kernel(
    const int*  __restrict__ conn, const int* __restrict__ target,
    const float* __restrict__ sym, const float* __restrict__ co,
    const unsigned short* __restrict__ Pr, const unsigned short* __restrict__ Pe,
    const unsigned short* __restrict__ Sy,
    const float* __restrict__ attn_w, const float* __restrict__ attn_b,
    const float* __restrict__ gate_w, const float* __restrict__ gate_wb,
    const float* __restrict__ gate_b,
    float* __restrict__ outp)
{
    __shared__ unsigned out_lds[CH * NDP];          // 20 KB, packed bf16 pairs
    __shared__ unsigned short rel_s[MM], ent_s[MM];
    __shared__ float co_s[MM];
    __shared__ float l_lds[CH];
    __shared__ float w_lds[CH];
    __shared__ float red[8];

    const int t = threadIdx.x;
    const int b = blockIdx.x;
    const int* cb = conn + b * (MM * 3);

    // indices + early-issued scattered co gather (kept in register)
    float co_reg = 0.f;
    if (t < MM) {
        int r = cb[t * 3 + 1];
        int e = cb[t * 3 + 2];
        rel_s[t] = (unsigned short)r;
        ent_s[t] = (unsigned short)e;
        int tgt = target[b * 2];                    // uniform
        co_reg = co[(long)e * NENT + tgt];          // scattered HBM read
    }
    __syncthreads();                                // S0

    const int g = t / NDP, dp = t % NDP;
    const bool act = (t < NG * NDP);
    const int lane = t & 63, wid = t >> 6;

    float oa0 = 0.f, oa1 = 0.f, nb0 = 0.f, nb1 = 0.f;
    float run_max = -3.0e38f, run_sum = 0.f;

    for (int c = 0; c < 2; ++c) {
        // ---- phase 2: out[ml][dp] = lrelu(Pr[rel]+Pe[ent]) (packed bf16)
        if (act) {
            #pragma unroll
            for (int it = 0; it < CH / NG; ++it) {
                int ml = g + NG * it;
                int m = c * CH + ml;
                int r = rel_s[m], e = ent_s[m];
                unsigned pru = *(const unsigned*)&Pr[r * DD + 2 * dp];
                unsigned peu = *(const unsigned*)&Pe[e * DD + 2 * dp];
                float x0 = bf16lo(pru) + bf16lo(peu);
                float x1 = bf16hi(pru) + bf16hi(peu);
                x0 = fmaxf(x0, 0.01f * x0);
                x1 = fmaxf(x1, 0.01f * x1);
                __hip_bfloat162 h = __float22bfloat162_rn(make_float2(x0, x1));
                out_lds[ml * NDP + dp] = *(unsigned*)&h;
            }
        }
        __syncthreads();                            // S1: out ready

        // ---- logits: t<200, thread = (ml, half); conflict-free stride 25
        float lacc = 0.f;
        if (t < 2 * CH) {
            int base = t * 25;                      // == (t>>1)*50 + (t&1)*25
            int doff = (t & 1) * 50;
            #pragma unroll
            for (int i = 0; i < 25; ++i) {
                unsigned u = out_lds[base + i];
                lacc = fmaf(bf16lo(u), attn_w[doff + 2 * i], lacc);
                lacc = fmaf(bf16hi(u), attn_w[doff + 2 * i + 1], lacc);
            }
        }
        float lother = __shfl_xor(lacc, 1);
        if (t < 2 * CH && (t & 1) == 0) l_lds[t >> 1] = lacc + lother + attn_b[0];
        if (c == 0 && t < MM) co_s[t] = co_reg;     // stash co before barrier
        __syncthreads();                            // S2: l_lds, co_s visible

        // ---- online softmax update
        float v = (t < CH) ? l_lds[t] : -3.0e38f;
        for (int off = 32; off >= 1; off >>= 1) v = fmaxf(v, __shfl_xor(v, off));
        if (lane == 0) red[wid] = v;
        __syncthreads();                            // S3
        float cmax = fmaxf(fmaxf(red[0], red[1]), fmaxf(red[2], red[3]));
        float new_max = fmaxf(run_max, cmax);
        float scale = __expf(run_max - new_max);    // chunk 0: exp(-inf)=0
        float e_v = (t < CH) ? __expf(l_lds[t] - new_max) : 0.f;
        if (t < CH) w_lds[t] = e_v;
        float s = e_v;
        for (int off = 32; off >= 1; off >>= 1) s += __shfl_xor(s, off);
        if (lane == 0) red[4 + wid] = s;
        __syncthreads();                            // S4: w_lds + red visible
        float csum = (red[4] + red[5]) + (red[6] + red[7]);
        run_sum = run_sum * scale + csum;
        run_max = new_max;
        oa0 *= scale; oa1 *= scale;

        // ---- phase 4: oa += w*out (LDS), nb += co_w*Sy (L2)
        if (act) {
            #pragma unroll
            for (int it = 0; it < CH / NG; ++it) {
                int ml = g + NG * it;
                int m = c * CH + ml;
                float w = w_lds[ml];
                unsigned u = out_lds[ml * NDP + dp];
                oa0 = fmaf(w, bf16lo(u), oa0);
                oa1 = fmaf(w, bf16hi(u), oa1);
                int e = ent_s[m];
                unsigned su = *(const unsigned*)&Sy[e * DD + 2 * dp];
                float cw = co_s[m];
                nb0 = fmaf(cw, bf16lo(su), nb0);
                nb1 = fmaf(cw, bf16hi(su), nb1);
            }
        }
        __syncthreads();                            // S5: out_lds reads done
    }

    // ---- finalize: normalize, reduce over g (reuse out_lds as f32 scratch)
    float inv = 1.f / run_sum;
    oa0 *= inv; oa1 *= inv;

    float* part = (float*)out_lds;                  // [5][100] oa, [5][100] nb
    if (act) {
        part[g * DD + 2 * dp]            = oa0;
        part[g * DD + 2 * dp + 1]        = oa1;
        part[NG * DD + g * DD + 2 * dp]     = nb0;
        part[NG * DD + g * DD + 2 * dp + 1] = nb1;
    }
    __syncthreads();                                // S6

    float oa = 0.f, nbv = 0.f;
    if (t < DD) {
        #pragma unroll
        for (int g2 = 0; g2 < NG; ++g2) {
            oa  += part[g2 * DD + t];
            nbv += part[NG * DD + g2 * DD + t];
        }
    }

    // gate = sigmoid(dot(oa, gate_w) + gwb + gb)
    float p = (t < DD) ? oa * gate_w[t] : 0.f;
    for (int off = 32; off >= 1; off >>= 1) p += __shfl_xor(p, off);
    if (lane == 0) red[wid] = p;
    __syncthreads();                                // S7
    float dot = (red[0] + red[1]) + (red[2] + red[3]);
    float gt = 1.f / (1.f + __expf(-(dot + gate_wb[0] + gate_b[0])));

    if (t < DD) {
        int s_self = cb[0];
        float self_v = sym[s_self * DD + t];        // f32, exact
        outp[b * DD + t] = oa * gt + self_v * (1.f - gt) + nbv;
    }
}

extern "C" void kernel_launch(void* const* d_in, const int* in_sizes, int n_in,
                              void* d_out, int out_size, void* d_ws, size_t ws_size,
                              hipStream_t stream) {
    const int*   conn    = (const int*)  d_in[0];
    const int*   target  = (const int*)  d_in[1];
    const float* sym     = (const float*)d_in[2];
    const float* co      = (const float*)d_in[3];
    const float* W       = (const float*)d_in[4];
    const float* wb      = (const float*)d_in[5];
    const float* gb      = (const float*)d_in[6];
    const float* attn_w  = (const float*)d_in[7];
    const float* attn_b  = (const float*)d_in[8];
    const float* gate_w  = (const float*)d_in[9];
    const float* gate_wb = (const float*)d_in[10];
    const float* gate_b  = (const float*)d_in[11];

    unsigned short* Pr = (unsigned short*)d_ws;
    unsigned short* Pe = (unsigned short*)((char*)d_ws + 1000000);
    unsigned short* Sy = (unsigned short*)((char*)d_ws + 2000000);

    precompute_kernel<<<(NENT * 50 + 255) / 256, 256, 0, stream>>>(
        sym, W, wb, gb, Pr, Pe, Sy);

    main_kernel<<<BB, 256, 0, stream>>>(
        conn, target, sym, co, Pr, Pe, Sy,
        attn_w, attn_b, gate_w, gate_wb, gate_b, (float*)d_out);
}